// Round 1
// baseline (239.793 us; speedup 1.0000x reference)
//
#include <hip/hip_runtime.h>
#include <math.h>

// Qwen3 MoE gate: logits = hidden @ W_gate^T ; softmax ; top-8 ; renorm.
// Outputs (flat float32 in d_out): sel_w [T*8], sel_idx-as-float [T*8], logits [T*64].
//
// Round 1 strategy: fp64 accumulation (exact fp32*fp32 products in double)
// so that top-k ORDERING matches the numpy reference exactly — index output
// is compared with an effectively-exact threshold and fp32 accumulation
// noise (~1e-6) vs expected 8th/9th logit gap (~0.068) would flip ~0.3
// tokens in expectation across 16384 tokens.

#define HDIM 2048
#define NEXP 64
#define TOPK 8
#define BK 128
#define TOK_PER_BLOCK 32
#define TOK_PER_WAVE 8

__global__ __launch_bounds__(256) void gate_gemm_f64(
    const float* __restrict__ hidden,   // [T, 2048]
    const float* __restrict__ wgate,    // [64, 2048]
    float* __restrict__ logits)         // [T, 64]
{
    // W tile: [64 experts][BK+1] — +1 pad => read bank = (129e+k)%32 = (e+k)%32,
    // 64 lanes with distinct e hit distinct banks (2 lanes/bank = free).
    __shared__ float Wt[NEXP][BK + 1];
    // H tile: [32 tokens][BK] — all lanes of a wave read the SAME address
    // (broadcast, conflict-free).
    __shared__ float Hs[TOK_PER_BLOCK][BK];

    const int tid  = threadIdx.x;
    const int wave = tid >> 6;        // 0..3 -> token group
    const int lane = tid & 63;        // expert id
    const int tokBase = blockIdx.x * TOK_PER_BLOCK;
    const int waveTokLocal = wave * TOK_PER_WAVE;

    double acc[TOK_PER_WAVE];
#pragma unroll
    for (int t = 0; t < TOK_PER_WAVE; ++t) acc[t] = 0.0;

    for (int k0 = 0; k0 < HDIM; k0 += BK) {
        // ---- stage W tile: 64x128 floats = 2048 float4, 8 per thread (coalesced)
#pragma unroll
        for (int p = 0; p < 8; ++p) {
            const int c  = tid + p * 256;
            const int e  = c >> 5;            // 0..63
            const int kq = (c & 31) << 2;     // 0,4,...,124
            const float4 w4 = *reinterpret_cast<const float4*>(
                &wgate[(size_t)e * HDIM + k0 + kq]);
            Wt[e][kq + 0] = w4.x;
            Wt[e][kq + 1] = w4.y;
            Wt[e][kq + 2] = w4.z;
            Wt[e][kq + 3] = w4.w;
        }
        // ---- stage H tile: 32x128 floats = 1024 float4, 4 per thread (coalesced)
#pragma unroll
        for (int p = 0; p < 4; ++p) {
            const int c  = tid + p * 256;
            const int t  = c >> 5;            // 0..31
            const int kq = (c & 31) << 2;
            const float4 h4 = *reinterpret_cast<const float4*>(
                &hidden[(size_t)(tokBase + t) * HDIM + k0 + kq]);
            *reinterpret_cast<float4*>(&Hs[t][kq]) = h4;
        }
        __syncthreads();

#pragma unroll 4
        for (int kk = 0; kk < BK; kk += 4) {
            const double w0 = (double)Wt[lane][kk + 0];
            const double w1 = (double)Wt[lane][kk + 1];
            const double w2 = (double)Wt[lane][kk + 2];
            const double w3 = (double)Wt[lane][kk + 3];
#pragma unroll
            for (int t = 0; t < TOK_PER_WAVE; ++t) {
                const float4 h4 = *reinterpret_cast<const float4*>(
                    &Hs[waveTokLocal + t][kk]);
                acc[t] += (double)h4.x * w0;
                acc[t] += (double)h4.y * w1;
                acc[t] += (double)h4.z * w2;
                acc[t] += (double)h4.w * w3;
            }
        }
        __syncthreads();
    }

    // epilogue: lanes e=0..63 consecutive -> coalesced 256B per token row
#pragma unroll
    for (int t = 0; t < TOK_PER_WAVE; ++t) {
        logits[(size_t)(tokBase + waveTokLocal + t) * NEXP + lane] = (float)acc[t];
    }
}

__global__ __launch_bounds__(256) void gate_topk(
    const float* __restrict__ logits,   // [T, 64]
    float* __restrict__ selw,           // [T, 8]
    float* __restrict__ selidx,         // [T, 8] written as float values
    int T)
{
    const int t = blockIdx.x * blockDim.x + threadIdx.x;
    if (t >= T) return;

    // 64 logits in registers, static indexing only (avoid scratch).
    float v[NEXP];
    const float4* row = reinterpret_cast<const float4*>(&logits[(size_t)t * NEXP]);
#pragma unroll
    for (int i = 0; i < NEXP / 4; ++i) {
        const float4 q = row[i];
        v[4 * i + 0] = q.x;
        v[4 * i + 1] = q.y;
        v[4 * i + 2] = q.z;
        v[4 * i + 3] = q.w;
    }

    float bv[TOPK];
    int   bidx[TOPK];
    unsigned long long used = 0ull;
    // 8 masked argmax passes; strict '>' scanning ascending i == jax.lax.top_k
    // tie-break (lowest index first).
#pragma unroll
    for (int k = 0; k < TOPK; ++k) {
        float best = -INFINITY;
        int   bi   = 0;
#pragma unroll
        for (int i = 0; i < NEXP; ++i) {
            const bool avail = ((used >> i) & 1ull) == 0ull;
            if (avail && v[i] > best) { best = v[i]; bi = i; }
        }
        bv[k]   = best;
        bidx[k] = bi;
        used |= (1ull << bi);
    }

    // softmax over all experts then renormalize over selected ==
    // exp(l_k - m) / sum_selected exp(l_j - m); m = global max = bv[0].
    const float m = bv[0];
    float ek[TOPK];
    float s = 0.f;
#pragma unroll
    for (int k = 0; k < TOPK; ++k) {
        ek[k] = expf(bv[k] - m);
        s += ek[k];
    }
    const float inv = 1.0f / s;
#pragma unroll
    for (int k = 0; k < TOPK; ++k) {
        selw[(size_t)t * TOPK + k]   = ek[k] * inv;
        selidx[(size_t)t * TOPK + k] = (float)bidx[k];
    }
}

extern "C" void kernel_launch(void* const* d_in, const int* in_sizes, int n_in,
                              void* d_out, int out_size, void* d_ws, size_t ws_size,
                              hipStream_t stream) {
    const float* hidden = (const float*)d_in[0];   // [4,4096,2048] f32
    const float* wgate  = (const float*)d_in[1];   // [64,2048] f32
    // d_in[2] = top_k scalar (8) — compile-time constant here.

    const int T = in_sizes[0] / HDIM;              // 16384 tokens

    float* out     = (float*)d_out;
    float* selw    = out;                          // T*8
    float* selidx  = out + (size_t)T * TOPK;       // T*8
    float* logits  = out + (size_t)2 * T * TOPK;   // T*64

    const int gemmBlocks = T / TOK_PER_BLOCK;      // 512
    gate_gemm_f64<<<gemmBlocks, 256, 0, stream>>>(hidden, wgate, logits);

    const int topkBlocks = (T + 255) / 256;        // 64
    gate_topk<<<topkBlocks, 256, 0, stream>>>(logits, selw, selidx, T);
}